// Round 3
// baseline (2175.015 us; speedup 1.0000x reference)
//
#include <hip/hip_runtime.h>
#include <hip/hip_bf16.h>
#include <math.h>

typedef __bf16 bf16x8 __attribute__((ext_vector_type(8)));
typedef float floatx4 __attribute__((ext_vector_type(4)));

#define T_LEN 128

// ws layout: bf16 fragment-packed weights. Gate region is ki-major now:
// slab s (=ki) at WP_OFF + s*65536, inside: ct*1024 + lane*16.
#define WP_OFF   0
#define WP_SZ    (64*10*64*16)     // 655360
#define W1P_OFF  (WP_OFF + WP_SZ)
#define W1P_SZ   (8*8*64*16)       // 65536
#define W2P_OFF  (W1P_OFF + W1P_SZ)
#define W2P_SZ   (8*4*64*16)       // 32768
#define WZP_OFF  (W2P_OFF + W2P_SZ)
#define WZP_SZ   (4*4*64*16)       // 16384
#define WS_NEEDED ((size_t)(WZP_OFF + WZP_SZ))   // 770048 B

// s_waitcnt imm: wait until <=N vmem outstanding (expcnt/lgkmcnt don't care)
#define WAITVM(N) (((N) & 0xF) | (0x7 << 4) | (0xF << 8) | (((N) >> 4) << 14))
// lgkmcnt(0), vmcnt/expcnt don't care
#define WAITKM0   0xC07F

// ---- fast transcendentals ------------------------------------------------
#if __has_builtin(__builtin_amdgcn_exp2f)
#define EXP2F(x) __builtin_amdgcn_exp2f(x)
#else
#define EXP2F(x) exp2f(x)
#endif
#if __has_builtin(__builtin_amdgcn_logf)
#define LOG2F(x) __builtin_amdgcn_logf(x)
#else
#define LOG2F(x) log2f(x)
#endif
#if __has_builtin(__builtin_amdgcn_rcpf)
#define RCPF(x) __builtin_amdgcn_rcpf(x)
#else
#define RCPF(x) (1.0f/(x))
#endif

__device__ __forceinline__ float fsigmoid(float x) {
    return RCPF(1.0f + EXP2F(-1.4426950408889634f * x));
}
__device__ __forceinline__ float ftanh(float x) {
    return 1.0f - 2.0f * RCPF(1.0f + EXP2F(2.8853900817779268f * x));
}

// async 16B/lane global->LDS DMA; LDS base wave-uniform, lands at +lane*16
__device__ __forceinline__ void dma16(const void* g, void* lds) {
    __builtin_amdgcn_global_load_lds(
        (const __attribute__((address_space(1))) void*)g,
        (__attribute__((address_space(3))) void*)lds,
        16, 0, 0);
}

// ---------------- prep: f32 weights -> bf16 B-fragment-linear in ws -------
// Gates now KI-MAJOR for contiguous 64KB per-ki slabs.
__global__ void prep_kernel(const float* __restrict__ Wih, const float* __restrict__ Whh,
                            const float* __restrict__ W1,  const float* __restrict__ W2,
                            const float* __restrict__ Wz,  unsigned char* __restrict__ ws)
{
    int id = blockIdx.x * blockDim.x + threadIdx.x;
    __bf16* Wp  = (__bf16*)(ws + WP_OFF);
    __bf16* W1p = (__bf16*)(ws + W1P_OFF);
    __bf16* W2p = (__bf16*)(ws + W2P_OFF);
    __bf16* Wzp = (__bf16*)(ws + WZP_OFF);
    if (id < 40960) {                       // gates: 64 ct x 10 ki x 64 lanes
        int ct = id / 640, rem = id % 640;
        int ki = rem / 64, lane = rem % 64;
        int row = ct * 16 + (lane & 15);                 // gate-output col
        int kb  = ki * 32 + (lane >> 4) * 8;
        for (int j = 0; j < 8; ++j) {
            int k = kb + j;
            float v;
            if (k < 40)       v = Wih[row * 40 + k];
            else if (k < 296) v = Whh[row * 256 + (k - 40)];
            else              v = 0.0f;                   // K-pad 296..319
            Wp[((size_t)(ki * 64 + ct) * 64 + lane) * 8 + j] = (__bf16)v;
        }
    } else if (id < 45056) {                // W1: 8 ct x 8 ki (ct-major)
        int id2 = id - 40960;
        int rem = id2 % 512, lane = rem % 64;
        int row = (id2 / 512) * 16 + (lane & 15);
        int kb  = (rem / 64) * 32 + (lane >> 4) * 8;
        for (int j = 0; j < 8; ++j) W1p[(size_t)id2 * 8 + j] = (__bf16)W1[row * 256 + kb + j];
    } else if (id < 47104) {                // W2: 8 ct x 4 ki
        int id3 = id - 45056;
        int rem = id3 % 256, lane = rem % 64;
        int row = (id3 / 256) * 16 + (lane & 15);
        int kb  = (rem / 64) * 32 + (lane >> 4) * 8;
        for (int j = 0; j < 8; ++j) W2p[(size_t)id3 * 8 + j] = (__bf16)W2[row * 128 + kb + j];
    } else if (id < 48128) {                // Wz: 4 ct x 4 ki
        int id4 = id - 47104;
        int rem = id4 % 256, lane = rem % 64;
        int row = (id4 / 256) * 16 + (lane & 15);
        int kb  = (rem / 64) * 32 + (lane >> 4) * 8;
        for (int j = 0; j < 8; ++j) Wzp[(size_t)id4 * 8 + j] = (__bf16)Wz[row * 128 + kb + j];
    }
}

// ---------------- fast path: producer/consumer wave specialization --------
// 64 blocks x 1024 threads, 16 batch rows/block.
// Waves 8-15: stream 12 slabs/step (10 gate-ki x 64KB, W1 64KB, W2|Wz 48KB)
//   into 2x64KB LDS double-buffer via global_load_lds, depth-2 counted vmcnt.
//   NEVER call __syncthreads after init; never vmcnt(0) in the loop.
// Waves 0-7: all MFMA + cell + z; sync among themselves via LDS counters.
// Slab protocol (all counters += 1 per wave per event, lane 0 only):
//   pdone: producer wave flags slab g after its loads for g are drained.
//   cdone: consumer wave flags slab g after it finished reading it.
//   producer issues slab g only when cdone >= 8*(g-1)  (buffer g-2 free)
//   consumer reads  slab g only when pdone >= 8*(g+1)  (slab g landed)
__global__ __launch_bounds__(1024)
__attribute__((amdgpu_waves_per_eu(4, 4)))
void seq_mfma(
    const float* __restrict__ A,   const float* __restrict__ eps,
    const float* __restrict__ z0,  const float* __restrict__ h0,
    const float* __restrict__ c0,
    const float* __restrict__ bih, const float* __restrict__ bhh,
    const float* __restrict__ b1,  const float* __restrict__ b2,
    const float* __restrict__ bz,
    const unsigned char* __restrict__ ws, float* __restrict__ out)
{
    const int tid  = threadIdx.x;
    const int wave = tid >> 6;
    const int lane = tid & 63;
    const int lrow = lane & 15;
    const int quad = lane >> 4;
    const int n0   = blockIdx.x * 16;
    const int w    = wave & 7;          // consumer wave id / clamped index

    __shared__ __align__(16) __bf16 slab[2][32768];   // 2 x 64 KB
    __shared__ __align__(16) __bf16 xh[2][16][328];   // [a(8)|z(32)|h(256)|pad]
    __shared__ __align__(16) __bf16 u1s[16][136];
    __shared__ __align__(16) __bf16 u2s[16][136];
    __shared__ int pdone, cdone, csyn;

    if (tid == 0) { pdone = 0; cdone = 0; csyn = 0; }

    // init both xh buffers: z0 | h0 | zero pad
    for (int idx = tid; idx < 2 * 16 * 320; idx += 1024) {
        int b = idx / (16 * 320);
        int rem = idx % (16 * 320);
        int r = rem / 320, col = 8 + rem % 320;
        float v;
        if (col < 40)       v = z0[col - 8];
        else if (col < 296) v = h0[col - 40];
        else                v = 0.0f;
        xh[b][r][col] = (__bf16)v;
    }
    // stage a(t=0) into buffer 0
    if (tid < 128)
        xh[0][tid >> 3][tid & 7] =
            (__bf16)A[((size_t)(n0 + (tid >> 3)) * T_LEN + 0) * 8 + (tid & 7)];

    __syncthreads();   // the ONLY workgroup barrier

    if (wave >= 8) {
        // ======================= PRODUCER =======================
        const int wp = wave - 8;
        const char* wsb = (const char*)ws;
        for (int g = 0; g < 12 * T_LEN; ++g) {
            const int s = g % 12;
            if (g >= 2) {   // wait: buffer (g-2) fully consumed
                const int tgt = 8 * (g - 1);
                while (*(volatile int*)&cdone < tgt) __builtin_amdgcn_s_sleep(2);
                __builtin_amdgcn_sched_barrier(0);
            }
            const char* src; int nIss;
            if (s < 10)       { src = wsb + WP_OFF + s * 65536; nIss = 8; }
            else if (s == 10) { src = wsb + W1P_OFF;            nIss = 8; }
            else              { src = wsb + W2P_OFF;            nIss = 6; }
            const int chunk = nIss * 1024;
            src += wp * chunk + lane * 16;
            char* dst = (char*)&slab[g & 1][0] + wp * chunk;
            for (int i = 0; i < nIss; ++i)
                dma16(src + i * 1024, dst + i * 1024);
            __builtin_amdgcn_sched_barrier(0);
            if (g >= 1) {   // drain slab g-1 (keep slab g in flight), flag it
                if (s == 11) __builtin_amdgcn_s_waitcnt(WAITVM(6));
                else         __builtin_amdgcn_s_waitcnt(WAITVM(8));
                __builtin_amdgcn_sched_barrier(0);
                if (lane == 0) atomicAdd(&pdone, 1);
            }
        }
        __builtin_amdgcn_s_waitcnt(WAITVM(0));
        __builtin_amdgcn_sched_barrier(0);
        if (lane == 0) atomicAdd(&pdone, 1);   // last slab
        return;
    }

    // ======================= CONSUMER =======================
#define WAIT_SLAB(G) do { const int tgt_ = 8 * ((G) + 1); \
        while (*(volatile int*)&pdone < tgt_) __builtin_amdgcn_s_sleep(1); \
        __builtin_amdgcn_sched_barrier(0); } while (0)
#define DONE_SLAB() do { __builtin_amdgcn_s_waitcnt(WAITKM0); \
        __builtin_amdgcn_sched_barrier(0); \
        if (lane == 0) atomicAdd(&cdone, 1); } while (0)
#define CSYNC(K) do { __builtin_amdgcn_s_waitcnt(WAITKM0); \
        __builtin_amdgcn_sched_barrier(0); \
        if (lane == 0) atomicAdd(&csyn, 1); \
        const int tgt_ = 8 * (4 * t + (K)); \
        while (*(volatile int*)&csyn < tgt_) __builtin_amdgcn_s_sleep(1); \
        __builtin_amdgcn_sched_barrier(0); } while (0)

    // biases (clamped indices are consumer-correct; producers never get here)
    float gb[4][2];
    #pragma unroll
    for (int g = 0; g < 4; ++g)
        #pragma unroll
        for (int j = 0; j < 2; ++j) {
            int unit = 32 * w + j * 16 + lrow;
            gb[g][j] = bih[g * 256 + unit] + bhh[g * 256 + unit];
        }
    float u1b = b1[w * 16 + lrow];
    float u2b = b2[w * 16 + lrow];
    float zbl = bz[(w & 1) * 16 + lrow];
    float zbr = bz[32 + (w & 1) * 16 + lrow];

    float cst[2][4];
    #pragma unroll
    for (int j = 0; j < 2; ++j) {
        float cv = c0[32 * w + j * 16 + lrow];
        #pragma unroll
        for (int r = 0; r < 4; ++r) cst[j][r] = cv;
    }

    for (int t = 0; t < T_LEN; ++t) {
        const int cb = t & 1;
        const int nb = cb ^ 1;

        // prefetch eps(t) and a(t+1): consumed ~5us later, no drains between
        float epsr[4] = {0,0,0,0};
        float a_nxt = 0.0f;
        if (w < 2) {
            #pragma unroll
            for (int r = 0; r < 4; ++r)
                epsr[r] = eps[((size_t)(n0 + quad * 4 + r) * T_LEN + t) * 32 + w * 16 + lrow];
            int idx = w * 64 + lane;
            if (t + 1 < T_LEN)
                a_nxt = A[((size_t)(n0 + (idx >> 3)) * T_LEN + (t + 1)) * 8 + (idx & 7)];
        }

        // ---- gates: 10 ki-slabs; wave w owns ct = g*16 + 2w + j
        floatx4 acc[4][2];
        #pragma unroll
        for (int g = 0; g < 4; ++g)
            #pragma unroll
            for (int j = 0; j < 2; ++j)
                acc[g][j] = (floatx4){gb[g][j], gb[g][j], gb[g][j], gb[g][j]};

        for (int s = 0; s < 10; ++s) {
            const int g = t * 12 + s;
            WAIT_SLAB(g);
            const __bf16* sb = &slab[g & 1][0];
            bf16x8 af = *(const bf16x8*)&xh[cb][lrow][s * 32 + quad * 8];
            #pragma unroll
            for (int gg = 0; gg < 4; ++gg)
                #pragma unroll
                for (int j = 0; j < 2; ++j) {
                    const int ct = gg * 16 + 2 * w + j;
                    bf16x8 b = *(const bf16x8*)(sb + ct * 512 + lane * 8);
                    acc[gg][j] = __builtin_amdgcn_mfma_f32_16x16x32_bf16(af, b, acc[gg][j], 0, 0, 0);
                }
            DONE_SLAB();
        }

        // ---- LSTM cell (own acc only), h -> xh[nb]
        #pragma unroll
        for (int j = 0; j < 2; ++j)
            #pragma unroll
            for (int r = 0; r < 4; ++r) {
                float iv = fsigmoid(acc[0][j][r]);
                float fv = fsigmoid(acc[1][j][r]);
                float gv = ftanh(acc[2][j][r]);
                float ov = fsigmoid(acc[3][j][r]);
                float cn = fv * cst[j][r] + iv * gv;
                cst[j][r] = cn;
                xh[nb][quad * 4 + r][40 + 32 * w + j * 16 + lrow] = (__bf16)(ov * ftanh(cn));
            }
        CSYNC(1);   // h staged

        // ---- u1 = relu(h @ W1^T + b1): slab 10, ct = w
        {
            const int g = t * 12 + 10;
            WAIT_SLAB(g);
            const __bf16* sb = &slab[g & 1][0];
            floatx4 a1 = (floatx4){u1b, u1b, u1b, u1b};
            #pragma unroll
            for (int ki = 0; ki < 8; ++ki) {
                bf16x8 af = *(const bf16x8*)&xh[nb][lrow][40 + ki * 32 + quad * 8];
                bf16x8 b  = *(const bf16x8*)(sb + (w * 8 + ki) * 512 + lane * 8);
                a1 = __builtin_amdgcn_mfma_f32_16x16x32_bf16(af, b, a1, 0, 0, 0);
            }
            #pragma unroll
            for (int r = 0; r < 4; ++r)
                u1s[quad * 4 + r][w * 16 + lrow] = (__bf16)fmaxf(a1[r], 0.0f);
            DONE_SLAB();   // W1 fully consumed
        }
        CSYNC(2);   // u1s ready

        // ---- u2 = relu(u1 @ W2^T + b2): slab 11 offset 0, ct = w
        const int g11 = t * 12 + 11;
        {
            WAIT_SLAB(g11);
            const __bf16* sb = &slab[g11 & 1][0];
            floatx4 a2 = (floatx4){u2b, u2b, u2b, u2b};
            #pragma unroll
            for (int ki = 0; ki < 4; ++ki) {
                bf16x8 af = *(const bf16x8*)&u1s[lrow][ki * 32 + quad * 8];
                bf16x8 b  = *(const bf16x8*)(sb + (w * 4 + ki) * 512 + lane * 8);
                a2 = __builtin_amdgcn_mfma_f32_16x16x32_bf16(af, b, a2, 0, 0, 0);
            }
            #pragma unroll
            for (int r = 0; r < 4; ++r)
                u2s[quad * 4 + r][w * 16 + lrow] = (__bf16)fmaxf(a2[r], 0.0f);
            // NOTE: no DONE_SLAB yet — Wz part of slab 11 still unread
        }
        CSYNC(3);   // u2s ready

        // ---- zz + z in waves 0-1 (loc ct=w, raw ct=w+2); Wz at +32768 B
        if (w < 2) {
            const __bf16* sb = &slab[g11 & 1][0] + 16384;
            floatx4 al = (floatx4){zbl, zbl, zbl, zbl};
            floatx4 ar = (floatx4){zbr, zbr, zbr, zbr};
            #pragma unroll
            for (int ki = 0; ki < 4; ++ki) {
                bf16x8 af = *(const bf16x8*)&u2s[lrow][ki * 32 + quad * 8];
                bf16x8 bl = *(const bf16x8*)(sb + ((w)     * 4 + ki) * 512 + lane * 8);
                bf16x8 br = *(const bf16x8*)(sb + ((w + 2) * 4 + ki) * 512 + lane * 8);
                al = __builtin_amdgcn_mfma_f32_16x16x32_bf16(af, bl, al, 0, 0, 0);
                ar = __builtin_amdgcn_mfma_f32_16x16x32_bf16(af, br, ar, 0, 0, 0);
            }
            #pragma unroll
            for (int r = 0; r < 4; ++r) {
                int row = quad * 4 + r;
                float raw = ar[r];
                float sp  = (raw > 20.0f)
                          ? raw
                          : 0.6931471805599453f *
                            LOG2F(1.0f + EXP2F(1.4426950408889634f * raw));
                float zv  = al[r] + sp * epsr[r];
                xh[nb][row][8 + w * 16 + lrow] = (__bf16)zv;
                out[((size_t)(n0 + row) * T_LEN + t) * 32 + w * 16 + lrow] = zv;
            }
            int idx = w * 64 + lane;
            xh[nb][idx >> 3][idx & 7] = (__bf16)a_nxt;   // a(t+1)
        }
        DONE_SLAB();   // slab 11 consumed (waves 0-1 gate this via program order)
        CSYNC(4);      // xh[nb] complete for next step
    }
#undef WAIT_SLAB
#undef DONE_SLAB
#undef CSYNC
}

// ---------------- fallback: proven R4 VALU kernel (f32 hard-coded) --------
struct SM {
    float zx[4][40]; float h[4][256]; float u1[4][128]; float u2[4][128]; float zz[4][64];
};

__global__ __launch_bounds__(256) void seq_valu(
    const float* __restrict__ A, const float* __restrict__ eps,
    const float* __restrict__ z0, const float* __restrict__ h0, const float* __restrict__ c0,
    const float* __restrict__ Wih, const float* __restrict__ Whh,
    const float* __restrict__ bih, const float* __restrict__ bhh,
    const float* __restrict__ W1, const float* __restrict__ b1,
    const float* __restrict__ W2, const float* __restrict__ b2,
    const float* __restrict__ Wz, const float* __restrict__ bz, float* __restrict__ out)
{
    __shared__ SM sm;
    const int tid = threadIdx.x;
    const int n0  = blockIdx.x * 4;
    if (tid < 128) { int rr = tid >> 5, cc = tid & 31; sm.zx[rr][8 + cc] = z0[cc]; }
    for (int i = tid; i < 4 * 256; i += 256) sm.h[i >> 8][i & 255] = h0[i & 255];
    float c[4];
    #pragma unroll
    for (int rr = 0; rr < 4; ++rr) c[rr] = c0[tid];
    float gbias[4];
    #pragma unroll
    for (int g = 0; g < 4; ++g) gbias[g] = bih[g * 256 + tid] + bhh[g * 256 + tid];

    for (int t = 0; t < T_LEN; ++t) {
        if (tid < 32) { int rr = tid >> 3, cc = tid & 7;
            sm.zx[rr][cc] = A[((size_t)(n0 + rr) * T_LEN + t) * 8 + cc]; }
        __syncthreads();
        float acc[4][4];
        #pragma unroll
        for (int g = 0; g < 4; ++g)
            #pragma unroll
            for (int rr = 0; rr < 4; ++rr) acc[g][rr] = gbias[g];
        for (int k = 0; k < 40; ++k) {
            float xv[4];
            #pragma unroll
            for (int rr = 0; rr < 4; ++rr) xv[rr] = sm.zx[rr][k];
            #pragma unroll
            for (int g = 0; g < 4; ++g) {
                float w = Wih[(size_t)(g * 256 + tid) * 40 + k];
                #pragma unroll
                for (int rr = 0; rr < 4; ++rr) acc[g][rr] += w * xv[rr];
            }
        }
        for (int k = 0; k < 256; ++k) {
            float hv[4];
            #pragma unroll
            for (int rr = 0; rr < 4; ++rr) hv[rr] = sm.h[rr][k];
            #pragma unroll
            for (int g = 0; g < 4; ++g) {
                float w = Whh[(size_t)(g * 256 + tid) * 256 + k];
                #pragma unroll
                for (int rr = 0; rr < 4; ++rr) acc[g][rr] += w * hv[rr];
            }
        }
        __syncthreads();
        #pragma unroll
        for (int rr = 0; rr < 4; ++rr) {
            float iv = 1.0f / (1.0f + expf(-acc[0][rr]));
            float fv = 1.0f / (1.0f + expf(-acc[1][rr]));
            float gv = tanhf(acc[2][rr]);
            float ov = 1.0f / (1.0f + expf(-acc[3][rr]));
            float cn = fv * c[rr] + iv * gv;
            c[rr] = cn;
            sm.h[rr][tid] = ov * tanhf(cn);
        }
        __syncthreads();
        { int col = tid & 127, rb = (tid >> 7) * 2;
          float a0 = b1[col], a1 = a0;
          for (int k = 0; k < 256; ++k) { float w = W1[(size_t)col * 256 + k];
              a0 += w * sm.h[rb][k]; a1 += w * sm.h[rb + 1][k]; }
          sm.u1[rb][col] = fmaxf(a0, 0.0f); sm.u1[rb + 1][col] = fmaxf(a1, 0.0f); }
        __syncthreads();
        { int col = tid & 127, rb = (tid >> 7) * 2;
          float a0 = b2[col], a1 = a0;
          for (int k = 0; k < 128; ++k) { float w = W2[(size_t)col * 128 + k];
              a0 += w * sm.u1[rb][k]; a1 += w * sm.u1[rb + 1][k]; }
          sm.u2[rb][col] = fmaxf(a0, 0.0f); sm.u2[rb + 1][col] = fmaxf(a1, 0.0f); }
        __syncthreads();
        { int rr = tid >> 6, col = tid & 63;
          float a0 = bz[col];
          for (int k = 0; k < 128; ++k) a0 += Wz[(size_t)col * 128 + k] * sm.u2[rr][k];
          sm.zz[rr][col] = a0; }
        __syncthreads();
        if (tid < 128) {
            int rr = tid >> 5, cc = tid & 31;
            float loc = sm.zz[rr][cc], raw = sm.zz[rr][cc + 32];
            float sp  = (raw > 20.0f) ? raw : log1pf(expf(raw));
            float ev  = eps[((size_t)(n0 + rr) * T_LEN + t) * 32 + cc];
            float zv  = loc + sp * ev;
            sm.zx[rr][8 + cc] = zv;
            out[((size_t)(n0 + rr) * T_LEN + t) * 32 + cc] = zv;
        }
        __syncthreads();
    }
}

extern "C" void kernel_launch(void* const* d_in, const int* in_sizes, int n_in,
                              void* d_out, int out_size, void* d_ws, size_t ws_size,
                              hipStream_t stream)
{
    const float* A   = (const float*)d_in[0];
    const float* eps = (const float*)d_in[1];
    const float* z0  = (const float*)d_in[2];
    const float* h0  = (const float*)d_in[3];
    const float* c0  = (const float*)d_in[4];
    const float* Wih = (const float*)d_in[5];
    const float* Whh = (const float*)d_in[6];
    const float* bih = (const float*)d_in[7];
    const float* bhh = (const float*)d_in[8];
    const float* W1  = (const float*)d_in[9];
    const float* b1  = (const float*)d_in[10];
    const float* W2  = (const float*)d_in[11];
    const float* b2  = (const float*)d_in[12];
    const float* Wz  = (const float*)d_in[13];
    const float* bz  = (const float*)d_in[14];
    float* out = (float*)d_out;

    if (ws_size >= WS_NEEDED) {
        prep_kernel<<<188, 256, 0, stream>>>(Wih, Whh, W1, W2, Wz, (unsigned char*)d_ws);
        seq_mfma<<<64, 1024, 0, stream>>>(A, eps, z0, h0, c0,
                                          bih, bhh, b1, b2, bz,
                                          (const unsigned char*)d_ws, out);
    } else {
        seq_valu<<<256, 256, 0, stream>>>(A, eps, z0, h0, c0, Wih, Whh, bih, bhh,
                                          W1, b1, W2, b2, Wz, bz, out);
    }
}